// Round 1
// baseline (418.092 us; speedup 1.0000x reference)
//
#include <hip/hip_runtime.h>
#include <math.h>

// Problem constants (S, B, D from reference).
#define S_LEN   2048
#define BATCH   32
#define DIM     1024
#define P_CHUNKS 32               // seq-split for flash-style partials
#define CHUNK   (S_LEN / P_CHUNKS) // 64 rows per block

// ---------------------------------------------------------------------------
// Skinny GEMM: out[b][d] = act( sum_k A[b][k] * W[d][k] ), b in [0,32).
// One wave per output column d (4 waves/block -> grid = Dout/4 blocks).
// A (32 x K) is staged in LDS in 256-wide K tiles; W is streamed coalesced.
// act: 0 = identity, 1 = tanh.
// ---------------------------------------------------------------------------
__global__ __launch_bounds__(256) void gemm_skinny(
    const float* __restrict__ A, const float* __restrict__ W,
    float* __restrict__ out, int K, int Dout, int act)
{
    __shared__ __align__(16) float At[32 * 256];  // 32 KiB

    const int t    = threadIdx.x;
    const int lane = t & 63;
    const int wid  = t >> 6;
    const int d    = blockIdx.x * 4 + wid;

    float acc[32];
#pragma unroll
    for (int b = 0; b < 32; ++b) acc[b] = 0.0f;

    for (int k0 = 0; k0 < K; k0 += 256) {
        // Stage A tile: 8192 floats = 2048 float4, 8 per thread, coalesced.
#pragma unroll
        for (int i = 0; i < 8; ++i) {
            int f4id = t + i * 256;
            int bb   = f4id >> 6;       // row (batch)
            int c4   = f4id & 63;       // float4 column within tile
            ((float4*)At)[bb * 64 + c4] =
                ((const float4*)(A + (size_t)bb * K + k0))[c4];
        }
        __syncthreads();

        // Wave reads its W row slice (coalesced float4).
        float4 w4 = ((const float4*)(W + (size_t)d * K + k0))[lane];

#pragma unroll
        for (int b = 0; b < 32; ++b) {
            float4 a4 = ((const float4*)At)[b * 64 + lane];
            acc[b] = fmaf(w4.x, a4.x, acc[b]);
            acc[b] = fmaf(w4.y, a4.y, acc[b]);
            acc[b] = fmaf(w4.z, a4.z, acc[b]);
            acc[b] = fmaf(w4.w, a4.w, acc[b]);
        }
        __syncthreads();
    }

    // Reduce each acc[b] across the 64 lanes; lane b keeps batch b's result.
    float mine = 0.0f;
#pragma unroll
    for (int b = 0; b < 32; ++b) {
        float v = acc[b];
#pragma unroll
        for (int off = 32; off > 0; off >>= 1) v += __shfl_xor(v, off, 64);
        if (lane == b) mine = v;
    }
    if (lane < 32) {
        float o = act ? tanhf(mine) : mine;
        out[(size_t)lane * Dout + d] = o;
    }
}

// ---------------------------------------------------------------------------
// Flash-style fused logits + online softmax + weighted-sum partials.
// Block = 256 threads handles CHUNK seq rows of one batch b.
// Per row: float4 load (prefetched), dot vs semi[b] (regs), block reduce
// (wave shuffle + 4-slot LDS, alternating buffer -> 1 barrier/row),
// online rescale of per-thread float4 accumulator.
// Writes partial (m, l, acc[1024]) for (b, chunk).
// ---------------------------------------------------------------------------
__global__ __launch_bounds__(256) void attn_partial(
    const float* __restrict__ input, const float* __restrict__ semi,
    float* __restrict__ pacc, float* __restrict__ pm, float* __restrict__ pl)
{
    const int p  = blockIdx.x;   // seq chunk
    const int b  = blockIdx.y;   // batch
    const int t  = threadIdx.x;
    const int lane = t & 63;
    const int wid  = t >> 6;
    const int s0 = p * CHUNK;

    __shared__ float red[2][4];

    const float4 sm4 = ((const float4*)(semi + (size_t)b * DIM))[t];
    const float4* rp =
        (const float4*)(input + ((size_t)s0 * BATCH + b) * DIM) + t;
    const int rstride = BATCH * DIM / 4;  // 8192 float4 between seq rows

    float m = -INFINITY, l = 0.0f;
    float4 acc = make_float4(0.f, 0.f, 0.f, 0.f);

    float4 xn = *rp;  // prefetch row 0
    for (int i = 0; i < CHUNK; ++i) {
        float4 x = xn;
        if (i + 1 < CHUNK) xn = rp[(i + 1) * rstride];  // prefetch next row

        // partial dot for this thread's 4 features
        float pd = x.x * sm4.x + x.y * sm4.y + x.z * sm4.z + x.w * sm4.w;
#pragma unroll
        for (int off = 32; off > 0; off >>= 1) pd += __shfl_xor(pd, off, 64);
        if (lane == 0) red[i & 1][wid] = pd;
        __syncthreads();
        float logit = red[i & 1][0] + red[i & 1][1]
                    + red[i & 1][2] + red[i & 1][3];

        // online softmax update
        float mn = fmaxf(m, logit);
        float sc = __expf(m - mn);       // exp(-inf - mn) = 0 on first row
        float f  = __expf(logit - mn);
        acc.x = fmaf(f, x.x, acc.x * sc);
        acc.y = fmaf(f, x.y, acc.y * sc);
        acc.z = fmaf(f, x.z, acc.z * sc);
        acc.w = fmaf(f, x.w, acc.w * sc);
        l = fmaf(l, sc, f);
        m = mn;
    }

    ((float4*)(pacc + ((size_t)b * P_CHUNKS + p) * DIM))[t] = acc;
    if (t == 0) {
        pm[b * P_CHUNKS + p] = m;
        pl[b * P_CHUNKS + p] = l;
    }
}

// ---------------------------------------------------------------------------
// Combine partials for batch b; write s_tilde into cat[:, :1024] and copy h
// into cat[:, 1024:]. Grid (32 batches x 4 d-quarters), 256 threads.
// ---------------------------------------------------------------------------
__global__ __launch_bounds__(256) void combine(
    const float* __restrict__ pacc, const float* __restrict__ pm,
    const float* __restrict__ pl, const float* __restrict__ h,
    float* __restrict__ cat)
{
    const int b = blockIdx.x;
    const int q = blockIdx.y;
    const int t = threadIdx.x;

    __shared__ float fsc[32];
    __shared__ float smv[32], slv[32];
    __shared__ float Linv;

    if (t < 32) {
        smv[t] = pm[b * P_CHUNKS + t];
        slv[t] = pl[b * P_CHUNKS + t];
    }
    __syncthreads();
    if (t == 0) {
        float M = -INFINITY;
        for (int pp = 0; pp < 32; ++pp) M = fmaxf(M, smv[pp]);
        float L = 0.0f;
        for (int pp = 0; pp < 32; ++pp) {
            float f = __expf(smv[pp] - M);
            fsc[pp] = f;
            L = fmaf(slv[pp], f, L);
        }
        Linv = 1.0f / L;
    }
    __syncthreads();

    const int d = q * 256 + t;
    float sum = 0.0f;
#pragma unroll
    for (int pp = 0; pp < 32; ++pp)
        sum = fmaf(fsc[pp], pacc[((size_t)b * P_CHUNKS + pp) * DIM + d], sum);

    cat[(size_t)b * (2 * DIM) + d]       = sum * Linv;
    cat[(size_t)b * (2 * DIM) + DIM + d] = h[(size_t)b * DIM + d];
}

// ---------------------------------------------------------------------------
extern "C" void kernel_launch(void* const* d_in, const int* in_sizes, int n_in,
                              void* d_out, int out_size, void* d_ws, size_t ws_size,
                              hipStream_t stream)
{
    const float* input = (const float*)d_in[0];  // [S, B, D]
    const float* h     = (const float*)d_in[1];  // [B, D]
    const float* Wi    = (const float*)d_in[2];  // [D, D]
    const float* Wo    = (const float*)d_in[3];  // [D, 2D]
    float* out = (float*)d_out;                  // [B, D]

    // Workspace carve (floats): semi | pacc | pm | pl | cat  (~4.4 MiB)
    float* ws   = (float*)d_ws;
    float* semi = ws;                                   // 32*1024
    float* pacc = semi + 32 * 1024;                     // 32*32*1024
    float* pm   = pacc + 32 * 32 * 1024;                // 1024
    float* pl   = pm + 1024;                            // 1024
    float* cat  = pl + 1024;                            // 32*2048

    // 1) semi = h @ Wi.T   (K=1024, Dout=1024)
    hipLaunchKernelGGL(gemm_skinny, dim3(256), dim3(256), 0, stream,
                       h, Wi, semi, 1024, 1024, 0);
    // 2) fused logits + online softmax + weighted-sum partials (reads input once)
    hipLaunchKernelGGL(attn_partial, dim3(P_CHUNKS, BATCH), dim3(256), 0, stream,
                       input, semi, pacc, pm, pl);
    // 3) combine partials -> cat = [s_tilde, h]
    hipLaunchKernelGGL(combine, dim3(BATCH, 4), dim3(256), 0, stream,
                       pacc, pm, pl, h, cat);
    // 4) out = tanh(cat @ Wo.T)   (K=2048, Dout=1024)
    hipLaunchKernelGGL(gemm_skinny, dim3(256), dim3(256), 0, stream,
                       cat, Wo, out, 2048, 1024, 1);
}